// Round 14
// baseline (299.242 us; speedup 1.0000x reference)
//
#include <hip/hip_runtime.h>
#include <math.h>

#define kB 128
#define kS 50
#define kD 64
#define kL 2
#define kItems 50000
#define kEps 1e-5f
#define PAD 68     // transformer f32 LDS row stride (floats)
#define NSTRIP 256
#define MROWS 16   // m-rows per logits tile-iter
#define NITER 200  // 3200 rows per m-half / 16
#define CPAD 260   // Cs row stride (floats)
#define GRIDX 200  // %8==0 for bijective XCD swizzle (4 idle strips)

// swizzled byte offset within a [64 rows x 128B] bf16 tile
#define SWB(r, byt) ((((r) * 128) + (byt)) ^ (((r) & 7) << 4))

typedef __bf16 bf16x8 __attribute__((ext_vector_type(8)));
typedef float  f32x4v __attribute__((ext_vector_type(4)));

__device__ __forceinline__ float wsum(float v) {
#pragma unroll
    for (int off = 32; off; off >>= 1) v += __shfl_xor(v, off, 64);
    return v;
}
__device__ __forceinline__ float wmax(float v) {
#pragma unroll
    for (int off = 32; off; off >>= 1) v = fmaxf(v, __shfl_xor(v, off, 64));
    return v;
}
__device__ __forceinline__ unsigned short f2bf(float x) {  // RNE
    unsigned u = __builtin_bit_cast(unsigned, x);
    u += 0x7FFFu + ((u >> 16) & 1u);
    return (unsigned short)(u >> 16);
}
__device__ __forceinline__ float dot4(const float4 a, const float4 b) {
    return fmaf(a.x, b.x, fmaf(a.y, b.y, fmaf(a.z, b.z, a.w * b.w)));
}

// One block (512 thr = 8 waves) per batch element. All 5 GEMMs/layer via MFMA.
// (unchanged from R12/R13)
__global__ __launch_bounds__(512) void transformer_kernel(
    const int* __restrict__ item_ids, const float* __restrict__ emb,
    const float* __restrict__ pos_emb,
    const float* __restrict__ Wq, const float* __restrict__ Wk,
    const float* __restrict__ Wv,
    const float* __restrict__ W1, const float* __restrict__ pb1,
    const float* __restrict__ W2, const float* __restrict__ pb2,
    const float* __restrict__ ln_g, const float* __restrict__ ln_b,
    unsigned short* __restrict__ Xb)   // [B*S, D] bf16 output
{
    const int b    = blockIdx.x;
    const int tid  = threadIdx.x;
    const int lane = tid & 63;
    const int wave = tid >> 6;

    __shared__ float xs[kS][PAD];
    __shared__ float qs[kS][PAD];
    __shared__ float ks[kS][PAD];
    __shared__ float vs[kS][PAD];
    __shared__ float as[kS][PAD];
    __shared__ float ps[8][64];
    __shared__ __align__(16) unsigned short xbf[64 * 64];
    __shared__ __align__(16) unsigned short hbf[64 * 64];
    __shared__ __align__(16) unsigned short Wb[3][64 * 64];

    for (int i = tid; i < kS * kD; i += 512) {
        int s = i >> 6, d = i & 63;
        int item = item_ids[b * kS + s];
        float v = emb[(size_t)item * kD + d] + pos_emb[s * kD + d];
        xs[s][d] = v;
        *(unsigned short*)((char*)xbf + SWB(s, d * 2)) = f2bf(v);
    }
    for (int i = tid; i < 14 * 8; i += 512) {
        int r = 50 + (i >> 3);
        int byt = SWB(r, (i & 7) * 16);
        *(ushort4*)((char*)xbf + byt) = (ushort4){0, 0, 0, 0};
        *(ushort4*)((char*)hbf + byt) = (ushort4){0, 0, 0, 0};
    }
    __syncthreads();

    const int frow = lane & 15;
    const int kq   = lane >> 4;
    const int mi   = wave & 3;
    const int ni0  = (wave >> 2) * 2;
    const int srow = mi * 16 + frow;

    for (int l = 0; l < kL; ++l) {
        const float* g  = ln_g + l * kD;
        const float* be = ln_b + l * kD;

        for (int i = tid; i < 3 * 64 * 16; i += 512) {
            int m  = i / (64 * 16);
            int r  = (i >> 4) & 63;
            int c4 = (i & 15) * 4;
            const float* W = (m == 0 ? Wq : m == 1 ? Wk : Wv) + l * kD * kD;
            float4 v = *(const float4*)&W[r * kD + c4];
            ushort4 u = {f2bf(v.x), f2bf(v.y), f2bf(v.z), f2bf(v.w)};
            *(ushort4*)((char*)Wb[m] + SWB(r, c4 * 2)) = u;
        }
        __syncthreads();

        {
            bf16x8 xb0 = *(const bf16x8*)((char*)xbf + SWB(srow, kq * 16));
            bf16x8 xb1 = *(const bf16x8*)((char*)xbf + SWB(srow, 64 + kq * 16));
#pragma unroll
            for (int m = 0; m < 3; ++m) {
                float* dst = (m == 0 ? &qs[0][0] : m == 1 ? &ks[0][0] : &vs[0][0]);
#pragma unroll
                for (int nn = 0; nn < 2; ++nn) {
                    int arow = (ni0 + nn) * 16 + frow;
                    bf16x8 a0 = *(const bf16x8*)((char*)Wb[m] + SWB(arow, kq * 16));
                    bf16x8 a1 = *(const bf16x8*)((char*)Wb[m] + SWB(arow, 64 + kq * 16));
                    f32x4v acc = (f32x4v){0.f, 0.f, 0.f, 0.f};
                    acc = __builtin_amdgcn_mfma_f32_16x16x32_bf16(a0, xb0, acc, 0, 0, 0);
                    acc = __builtin_amdgcn_mfma_f32_16x16x32_bf16(a1, xb1, acc, 0, 0, 0);
                    if (srow < kS) {
                        int e0 = (ni0 + nn) * 16 + kq * 4;
#pragma unroll
                        for (int r4 = 0; r4 < 4; ++r4)
                            dst[srow * PAD + e0 + r4] = acc[r4];
                    }
                }
            }
        }
        __syncthreads();

        for (int q = wave; q < kS; q += 8) {
            int k = lane;
            float sc = -INFINITY;
            if (k <= q) {
                const float4* qv = (const float4*)&qs[q][0];
                const float4* kv = (const float4*)&ks[k][0];
                float acc = 0.f;
#pragma unroll
                for (int d4 = 0; d4 < 16; ++d4) acc += dot4(qv[d4], kv[d4]);
                sc = acc * 0.125f;
            }
            float mx = wmax(sc);
            float ev = (k <= q) ? __expf(sc - mx) : 0.f;
            float sm = wsum(ev);
            ps[wave][lane] = ev / sm;
            float acc = 0.f;
#pragma unroll
            for (int kk = 0; kk < kS; ++kk)
                acc = fmaf(ps[wave][kk], vs[kk][lane], acc);
            as[q][lane] = acc;
        }
        __syncthreads();

        for (int s = wave; s < kS; s += 8) {
            float v  = xs[s][lane] + as[s][lane];
            float mu = wsum(v) * (1.f / 64.f);
            float dv = v - mu;
            float var = wsum(dv * dv) * (1.f / 64.f);
            float o = fmaf(g[lane] * dv, rsqrtf(var + kEps), be[lane]);
            xs[s][lane] = o;
            *(unsigned short*)((char*)xbf + SWB(s, lane * 2)) = f2bf(o);
        }
        for (int i = tid; i < 2 * 64 * 16; i += 512) {
            int m  = i / (64 * 16);
            int r  = (i >> 4) & 63;
            int c4 = (i & 15) * 4;
            const float* W = (m == 0 ? W1 : W2) + l * kD * kD;
            float4 v = *(const float4*)&W[r * kD + c4];
            ushort4 u = {f2bf(v.x), f2bf(v.y), f2bf(v.z), f2bf(v.w)};
            *(ushort4*)((char*)Wb[m] + SWB(r, c4 * 2)) = u;
        }
        __syncthreads();

        {
            bf16x8 xb0 = *(const bf16x8*)((char*)xbf + SWB(srow, kq * 16));
            bf16x8 xb1 = *(const bf16x8*)((char*)xbf + SWB(srow, 64 + kq * 16));
#pragma unroll
            for (int nn = 0; nn < 2; ++nn) {
                int arow = (ni0 + nn) * 16 + frow;
                bf16x8 a0 = *(const bf16x8*)((char*)Wb[0] + SWB(arow, kq * 16));
                bf16x8 a1 = *(const bf16x8*)((char*)Wb[0] + SWB(arow, 64 + kq * 16));
                f32x4v acc = (f32x4v){0.f, 0.f, 0.f, 0.f};
                acc = __builtin_amdgcn_mfma_f32_16x16x32_bf16(a0, xb0, acc, 0, 0, 0);
                acc = __builtin_amdgcn_mfma_f32_16x16x32_bf16(a1, xb1, acc, 0, 0, 0);
                if (srow < kS) {
                    int e0 = (ni0 + nn) * 16 + kq * 4;
                    float4 bi = *(const float4*)&pb1[l * kD + e0];
                    ushort4 u;
                    u.x = f2bf(fmaxf(acc[0] + bi.x, 0.f));
                    u.y = f2bf(fmaxf(acc[1] + bi.y, 0.f));
                    u.z = f2bf(fmaxf(acc[2] + bi.z, 0.f));
                    u.w = f2bf(fmaxf(acc[3] + bi.w, 0.f));
                    *(ushort4*)((char*)hbf + SWB(srow, e0 * 2)) = u;
                }
            }
        }
        __syncthreads();

        {
            bf16x8 hb0 = *(const bf16x8*)((char*)hbf + SWB(srow, kq * 16));
            bf16x8 hb1 = *(const bf16x8*)((char*)hbf + SWB(srow, 64 + kq * 16));
#pragma unroll
            for (int nn = 0; nn < 2; ++nn) {
                int arow = (ni0 + nn) * 16 + frow;
                bf16x8 a0 = *(const bf16x8*)((char*)Wb[1] + SWB(arow, kq * 16));
                bf16x8 a1 = *(const bf16x8*)((char*)Wb[1] + SWB(arow, 64 + kq * 16));
                f32x4v acc = (f32x4v){0.f, 0.f, 0.f, 0.f};
                acc = __builtin_amdgcn_mfma_f32_16x16x32_bf16(a0, hb0, acc, 0, 0, 0);
                acc = __builtin_amdgcn_mfma_f32_16x16x32_bf16(a1, hb1, acc, 0, 0, 0);
                if (srow < kS) {
                    int e0 = (ni0 + nn) * 16 + kq * 4;
                    float4 bi = *(const float4*)&pb2[l * kD + e0];
                    qs[srow][e0 + 0] = acc[0] + bi.x;
                    qs[srow][e0 + 1] = acc[1] + bi.y;
                    qs[srow][e0 + 2] = acc[2] + bi.z;
                    qs[srow][e0 + 3] = acc[3] + bi.w;
                }
            }
        }
        __syncthreads();

        for (int s = wave; s < kS; s += 8) {
            float v  = xs[s][lane] + qs[s][lane];
            float mu = wsum(v) * (1.f / 64.f);
            float dv = v - mu;
            float var = wsum(dv * dv) * (1.f / 64.f);
            float o = fmaf(g[lane] * dv, rsqrtf(var + kEps), be[lane]);
            xs[s][lane] = o;
            *(unsigned short*)((char*)xbf + SWB(s, lane * 2)) = f2bf(o);
        }
        __syncthreads();
    }

    for (int i = tid; i < kS * kD; i += 512) {
        int s = i >> 6, d = i & 63;
        Xb[(size_t)(b * kS + s) * kD + d] = f2bf(xs[s][d]);
    }
}

// logits: R13 structure; ONE change — Cs single-buffered (LDS 65.3->49.4KB
// => 3 blocks/CU instead of 2, +50% concurrent store streams). Two LDS-only
// barriers per iter (R6 vs R7 showed 2-bar ~= 1-bar). nt stores; no vmcnt
// drain in-loop; XCD n-banding kept.
__global__ __launch_bounds__(512) void logits_kernel(
    const unsigned short* __restrict__ Xb, const float* __restrict__ E,
    float* __restrict__ out)
{
    const int xcd   = blockIdx.x & 7;
    const int strip = xcd * 25 + (blockIdx.x >> 3);
    const int n0    = strip * NSTRIP;
    if (n0 >= kItems) return;

    const int tid  = threadIdx.x;
    const int lane = tid & 63;
    const int wave = tid >> 6;
    const int mrow0 = blockIdx.y * (NITER * MROWS);

    __shared__ __align__(16) unsigned short Es[NSTRIP * kD];   // 32KB
    __shared__ __align__(16) float Cs[MROWS][CPAD];            // 16.6KB (single)

    for (int i = tid; i < NSTRIP * 16; i += 512) {
        int r  = i >> 4;
        int c4 = (i & 15) * 4;
        int n  = n0 + r;
        float4 v = (n < kItems) ? *(const float4*)&E[(size_t)n * kD + c4]
                                : make_float4(0.f, 0.f, 0.f, 0.f);
        ushort4 u;
        u.x = f2bf(v.x); u.y = f2bf(v.y); u.z = f2bf(v.z); u.w = f2bf(v.w);
        int byt = (r * 128 + c4 * 2) ^ ((r & 7) << 4);
        *(ushort4*)((char*)Es + byt) = u;
    }
    __syncthreads();

    const int frow = lane & 15;
    const int kq   = lane >> 4;

    bf16x8 efrag[2][2];
#pragma unroll
    for (int nc = 0; nc < 2; ++nc) {
        int brow = wave * 32 + nc * 16 + frow;
        int base = brow * 128 + kq * 16;
        int swz  = (brow & 7) << 4;
        efrag[nc][0] = *(const bf16x8*)((const char*)Es + ((base) ^ swz));
        efrag[nc][1] = *(const bf16x8*)((const char*)Es + ((base + 64) ^ swz));
    }

    const unsigned short* xp = Xb + (size_t)(mrow0 + frow) * kD + kq * 8;
    const bool ncol_ok = (n0 + lane * 4 + 3) < kItems;

    bf16x8 xc0 = *(const bf16x8*)(xp);
    bf16x8 xc1 = *(const bf16x8*)(xp + 32);

    for (int t = 0; t < NITER; ++t) {
        // prefetch next tile's X fragments (loads precede stores in vmcnt order)
        bf16x8 xn0, xn1;
        if (t + 1 < NITER) {
            xn0 = *(const bf16x8*)(xp + (size_t)(t + 1) * MROWS * kD);
            xn1 = *(const bf16x8*)(xp + (size_t)(t + 1) * MROWS * kD + 32);
        }

        // MFMA tile t
        f32x4v acc[2];
#pragma unroll
        for (int nc = 0; nc < 2; ++nc) {
            acc[nc] = (f32x4v){0.f, 0.f, 0.f, 0.f};
            acc[nc] = __builtin_amdgcn_mfma_f32_16x16x32_bf16(efrag[nc][0], xc0, acc[nc], 0, 0, 0);
            acc[nc] = __builtin_amdgcn_mfma_f32_16x16x32_bf16(efrag[nc][1], xc1, acc[nc], 0, 0, 0);
        }

        // corner-turn into Cs
#pragma unroll
        for (int nc = 0; nc < 2; ++nc)
            *(f32x4v*)&Cs[frow][wave * 32 + nc * 16 + kq * 4] = acc[nc];

        __builtin_amdgcn_sched_barrier(0);
        asm volatile("s_waitcnt lgkmcnt(0)" ::: "memory");
        __builtin_amdgcn_s_barrier();
        __builtin_amdgcn_sched_barrier(0);

        // store tile t: 2 rows/wave, 1KB contiguous nt each
        {
            const int mbase = mrow0 + t * MROWS;
#pragma unroll
            for (int rr = 0; rr < 2; ++rr) {
                int r = wave * 2 + rr;
                f32x4v v = *(const f32x4v*)&Cs[r][lane * 4];
                if (ncol_ok)
                    __builtin_nontemporal_store(v,
                        (f32x4v*)(out + (size_t)(mbase + r) * kItems + n0 + lane * 4));
            }
        }

        __builtin_amdgcn_sched_barrier(0);
        asm volatile("s_waitcnt lgkmcnt(0)" ::: "memory");
        __builtin_amdgcn_s_barrier();
        __builtin_amdgcn_sched_barrier(0);

        xc0 = xn0; xc1 = xn1;
    }
}

extern "C" void kernel_launch(void* const* d_in, const int* in_sizes, int n_in,
                              void* d_out, int out_size, void* d_ws, size_t ws_size,
                              hipStream_t stream) {
    const int*   item_ids = (const int*)d_in[0];
    const float* emb      = (const float*)d_in[1];
    const float* pos_emb  = (const float*)d_in[2];
    const float* Wq       = (const float*)d_in[3];
    const float* Wk       = (const float*)d_in[4];
    const float* Wv       = (const float*)d_in[5];
    const float* W1       = (const float*)d_in[6];
    const float* b1       = (const float*)d_in[7];
    const float* W2       = (const float*)d_in[8];
    const float* b2       = (const float*)d_in[9];
    const float* ln_g     = (const float*)d_in[10];
    const float* ln_b     = (const float*)d_in[11];

    unsigned short* Xb = (unsigned short*)d_ws;   // [B*S, D] bf16, 0.8 MB
    float* out = (float*)d_out;

    transformer_kernel<<<kB, 512, 0, stream>>>(item_ids, emb, pos_emb,
                                               Wq, Wk, Wv, W1, b1, W2, b2,
                                               ln_g, ln_b, Xb);
    dim3 grid(GRIDX, 2);   // 200 x 2 (8 idle pad blocks)
    logits_kernel<<<grid, 512, 0, stream>>>(Xb, emb, out);
}

// Round 15
// 272.463 us; speedup vs baseline: 1.0983x; 1.0983x over previous
//
#include <hip/hip_runtime.h>
#include <math.h>

#define kB 128
#define kS 50
#define kD 64
#define kL 2
#define kItems 50000
#define kEps 1e-5f
#define PAD 68     // transformer f32 LDS row stride (floats)
#define NSTRIP 256
#define MROWS 16   // m-rows per logits tile-iter
#define NITER 200  // 3200 rows per m-half / 16
#define CPAD 260   // Cs row stride (floats)
#define GRIDX 200  // %8==0 for bijective XCD swizzle (4 idle strips)

// swizzled byte offset within a [64 rows x 128B] bf16 tile
#define SWB(r, byt) ((((r) * 128) + (byt)) ^ (((r) & 7) << 4))

typedef __bf16 bf16x8 __attribute__((ext_vector_type(8)));
typedef float  f32x4v __attribute__((ext_vector_type(4)));

__device__ __forceinline__ float wsum(float v) {
#pragma unroll
    for (int off = 32; off; off >>= 1) v += __shfl_xor(v, off, 64);
    return v;
}
__device__ __forceinline__ float wmax(float v) {
#pragma unroll
    for (int off = 32; off; off >>= 1) v = fmaxf(v, __shfl_xor(v, off, 64));
    return v;
}
__device__ __forceinline__ unsigned short f2bf(float x) {  // RNE
    unsigned u = __builtin_bit_cast(unsigned, x);
    u += 0x7FFFu + ((u >> 16) & 1u);
    return (unsigned short)(u >> 16);
}
__device__ __forceinline__ float dot4(const float4 a, const float4 b) {
    return fmaf(a.x, b.x, fmaf(a.y, b.y, fmaf(a.z, b.z, a.w * b.w)));
}

// One block (512 thr = 8 waves) per batch element. All 5 GEMMs/layer via MFMA.
// (unchanged from R12/R13)
__global__ __launch_bounds__(512) void transformer_kernel(
    const int* __restrict__ item_ids, const float* __restrict__ emb,
    const float* __restrict__ pos_emb,
    const float* __restrict__ Wq, const float* __restrict__ Wk,
    const float* __restrict__ Wv,
    const float* __restrict__ W1, const float* __restrict__ pb1,
    const float* __restrict__ W2, const float* __restrict__ pb2,
    const float* __restrict__ ln_g, const float* __restrict__ ln_b,
    unsigned short* __restrict__ Xb)   // [B*S, D] bf16 output
{
    const int b    = blockIdx.x;
    const int tid  = threadIdx.x;
    const int lane = tid & 63;
    const int wave = tid >> 6;

    __shared__ float xs[kS][PAD];
    __shared__ float qs[kS][PAD];
    __shared__ float ks[kS][PAD];
    __shared__ float vs[kS][PAD];
    __shared__ float as[kS][PAD];
    __shared__ float ps[8][64];
    __shared__ __align__(16) unsigned short xbf[64 * 64];
    __shared__ __align__(16) unsigned short hbf[64 * 64];
    __shared__ __align__(16) unsigned short Wb[3][64 * 64];

    for (int i = tid; i < kS * kD; i += 512) {
        int s = i >> 6, d = i & 63;
        int item = item_ids[b * kS + s];
        float v = emb[(size_t)item * kD + d] + pos_emb[s * kD + d];
        xs[s][d] = v;
        *(unsigned short*)((char*)xbf + SWB(s, d * 2)) = f2bf(v);
    }
    for (int i = tid; i < 14 * 8; i += 512) {
        int r = 50 + (i >> 3);
        int byt = SWB(r, (i & 7) * 16);
        *(ushort4*)((char*)xbf + byt) = (ushort4){0, 0, 0, 0};
        *(ushort4*)((char*)hbf + byt) = (ushort4){0, 0, 0, 0};
    }
    __syncthreads();

    const int frow = lane & 15;
    const int kq   = lane >> 4;
    const int mi   = wave & 3;
    const int ni0  = (wave >> 2) * 2;
    const int srow = mi * 16 + frow;

    for (int l = 0; l < kL; ++l) {
        const float* g  = ln_g + l * kD;
        const float* be = ln_b + l * kD;

        for (int i = tid; i < 3 * 64 * 16; i += 512) {
            int m  = i / (64 * 16);
            int r  = (i >> 4) & 63;
            int c4 = (i & 15) * 4;
            const float* W = (m == 0 ? Wq : m == 1 ? Wk : Wv) + l * kD * kD;
            float4 v = *(const float4*)&W[r * kD + c4];
            ushort4 u = {f2bf(v.x), f2bf(v.y), f2bf(v.z), f2bf(v.w)};
            *(ushort4*)((char*)Wb[m] + SWB(r, c4 * 2)) = u;
        }
        __syncthreads();

        {
            bf16x8 xb0 = *(const bf16x8*)((char*)xbf + SWB(srow, kq * 16));
            bf16x8 xb1 = *(const bf16x8*)((char*)xbf + SWB(srow, 64 + kq * 16));
#pragma unroll
            for (int m = 0; m < 3; ++m) {
                float* dst = (m == 0 ? &qs[0][0] : m == 1 ? &ks[0][0] : &vs[0][0]);
#pragma unroll
                for (int nn = 0; nn < 2; ++nn) {
                    int arow = (ni0 + nn) * 16 + frow;
                    bf16x8 a0 = *(const bf16x8*)((char*)Wb[m] + SWB(arow, kq * 16));
                    bf16x8 a1 = *(const bf16x8*)((char*)Wb[m] + SWB(arow, 64 + kq * 16));
                    f32x4v acc = (f32x4v){0.f, 0.f, 0.f, 0.f};
                    acc = __builtin_amdgcn_mfma_f32_16x16x32_bf16(a0, xb0, acc, 0, 0, 0);
                    acc = __builtin_amdgcn_mfma_f32_16x16x32_bf16(a1, xb1, acc, 0, 0, 0);
                    if (srow < kS) {
                        int e0 = (ni0 + nn) * 16 + kq * 4;
#pragma unroll
                        for (int r4 = 0; r4 < 4; ++r4)
                            dst[srow * PAD + e0 + r4] = acc[r4];
                    }
                }
            }
        }
        __syncthreads();

        for (int q = wave; q < kS; q += 8) {
            int k = lane;
            float sc = -INFINITY;
            if (k <= q) {
                const float4* qv = (const float4*)&qs[q][0];
                const float4* kv = (const float4*)&ks[k][0];
                float acc = 0.f;
#pragma unroll
                for (int d4 = 0; d4 < 16; ++d4) acc += dot4(qv[d4], kv[d4]);
                sc = acc * 0.125f;
            }
            float mx = wmax(sc);
            float ev = (k <= q) ? __expf(sc - mx) : 0.f;
            float sm = wsum(ev);
            ps[wave][lane] = ev / sm;
            float acc = 0.f;
#pragma unroll
            for (int kk = 0; kk < kS; ++kk)
                acc = fmaf(ps[wave][kk], vs[kk][lane], acc);
            as[q][lane] = acc;
        }
        __syncthreads();

        for (int s = wave; s < kS; s += 8) {
            float v  = xs[s][lane] + as[s][lane];
            float mu = wsum(v) * (1.f / 64.f);
            float dv = v - mu;
            float var = wsum(dv * dv) * (1.f / 64.f);
            float o = fmaf(g[lane] * dv, rsqrtf(var + kEps), be[lane]);
            xs[s][lane] = o;
            *(unsigned short*)((char*)xbf + SWB(s, lane * 2)) = f2bf(o);
        }
        for (int i = tid; i < 2 * 64 * 16; i += 512) {
            int m  = i / (64 * 16);
            int r  = (i >> 4) & 63;
            int c4 = (i & 15) * 4;
            const float* W = (m == 0 ? W1 : W2) + l * kD * kD;
            float4 v = *(const float4*)&W[r * kD + c4];
            ushort4 u = {f2bf(v.x), f2bf(v.y), f2bf(v.z), f2bf(v.w)};
            *(ushort4*)((char*)Wb[m] + SWB(r, c4 * 2)) = u;
        }
        __syncthreads();

        {
            bf16x8 xb0 = *(const bf16x8*)((char*)xbf + SWB(srow, kq * 16));
            bf16x8 xb1 = *(const bf16x8*)((char*)xbf + SWB(srow, 64 + kq * 16));
#pragma unroll
            for (int nn = 0; nn < 2; ++nn) {
                int arow = (ni0 + nn) * 16 + frow;
                bf16x8 a0 = *(const bf16x8*)((char*)Wb[0] + SWB(arow, kq * 16));
                bf16x8 a1 = *(const bf16x8*)((char*)Wb[0] + SWB(arow, 64 + kq * 16));
                f32x4v acc = (f32x4v){0.f, 0.f, 0.f, 0.f};
                acc = __builtin_amdgcn_mfma_f32_16x16x32_bf16(a0, xb0, acc, 0, 0, 0);
                acc = __builtin_amdgcn_mfma_f32_16x16x32_bf16(a1, xb1, acc, 0, 0, 0);
                if (srow < kS) {
                    int e0 = (ni0 + nn) * 16 + kq * 4;
                    float4 bi = *(const float4*)&pb1[l * kD + e0];
                    ushort4 u;
                    u.x = f2bf(fmaxf(acc[0] + bi.x, 0.f));
                    u.y = f2bf(fmaxf(acc[1] + bi.y, 0.f));
                    u.z = f2bf(fmaxf(acc[2] + bi.z, 0.f));
                    u.w = f2bf(fmaxf(acc[3] + bi.w, 0.f));
                    *(ushort4*)((char*)hbf + SWB(srow, e0 * 2)) = u;
                }
            }
        }
        __syncthreads();

        {
            bf16x8 hb0 = *(const bf16x8*)((char*)hbf + SWB(srow, kq * 16));
            bf16x8 hb1 = *(const bf16x8*)((char*)hbf + SWB(srow, 64 + kq * 16));
#pragma unroll
            for (int nn = 0; nn < 2; ++nn) {
                int arow = (ni0 + nn) * 16 + frow;
                bf16x8 a0 = *(const bf16x8*)((char*)Wb[1] + SWB(arow, kq * 16));
                bf16x8 a1 = *(const bf16x8*)((char*)Wb[1] + SWB(arow, 64 + kq * 16));
                f32x4v acc = (f32x4v){0.f, 0.f, 0.f, 0.f};
                acc = __builtin_amdgcn_mfma_f32_16x16x32_bf16(a0, hb0, acc, 0, 0, 0);
                acc = __builtin_amdgcn_mfma_f32_16x16x32_bf16(a1, hb1, acc, 0, 0, 0);
                if (srow < kS) {
                    int e0 = (ni0 + nn) * 16 + kq * 4;
                    float4 bi = *(const float4*)&pb2[l * kD + e0];
                    qs[srow][e0 + 0] = acc[0] + bi.x;
                    qs[srow][e0 + 1] = acc[1] + bi.y;
                    qs[srow][e0 + 2] = acc[2] + bi.z;
                    qs[srow][e0 + 3] = acc[3] + bi.w;
                }
            }
        }
        __syncthreads();

        for (int s = wave; s < kS; s += 8) {
            float v  = xs[s][lane] + qs[s][lane];
            float mu = wsum(v) * (1.f / 64.f);
            float dv = v - mu;
            float var = wsum(dv * dv) * (1.f / 64.f);
            float o = fmaf(g[lane] * dv, rsqrtf(var + kEps), be[lane]);
            xs[s][lane] = o;
            *(unsigned short*)((char*)xbf + SWB(s, lane * 2)) = f2bf(o);
        }
        __syncthreads();
    }

    for (int i = tid; i < kS * kD; i += 512) {
        int s = i >> 6, d = i & 63;
        Xb[(size_t)(b * kS + s) * kD + d] = f2bf(xs[s][d]);
    }
}

// logits: EXACT R13 loop structure (273us best). ONE change: Es and Cs now
// ALIAS the same LDS (Es is dead after the efrag hoist -> union legal with a
// barrier). LDS 65.3KB -> 33.3KB => 3 blocks/CU (VGPR-capped) instead of 2,
// +50% concurrent store streams, all 400 blocks co-resident. Single-variable
// occupancy test without R14's structural damage.
__global__ __launch_bounds__(512) void logits_kernel(
    const unsigned short* __restrict__ Xb, const float* __restrict__ E,
    float* __restrict__ out)
{
    const int xcd   = blockIdx.x & 7;
    const int strip = xcd * 25 + (blockIdx.x >> 3);
    const int n0    = strip * NSTRIP;
    if (n0 >= kItems) return;

    const int tid  = threadIdx.x;
    const int lane = tid & 63;
    const int wave = tid >> 6;
    const int mrow0 = blockIdx.y * (NITER * MROWS);

    // union: Es (32KB, startup only) aliases Cs[2] (33.3KB, main loop)
    __shared__ __align__(16) char shraw[2 * MROWS * CPAD * 4];
    unsigned short* Es = (unsigned short*)shraw;
    typedef float CsRow[CPAD];
    CsRow* Cs0 = (CsRow*)shraw;                          // Cs[0]
    CsRow* Cs1 = (CsRow*)(shraw + MROWS * CPAD * 4);     // Cs[1]

    for (int i = tid; i < NSTRIP * 16; i += 512) {
        int r  = i >> 4;
        int c4 = (i & 15) * 4;
        int n  = n0 + r;
        float4 v = (n < kItems) ? *(const float4*)&E[(size_t)n * kD + c4]
                                : make_float4(0.f, 0.f, 0.f, 0.f);
        ushort4 u;
        u.x = f2bf(v.x); u.y = f2bf(v.y); u.z = f2bf(v.z); u.w = f2bf(v.w);
        int byt = (r * 128 + c4 * 2) ^ ((r & 7) << 4);
        *(ushort4*)((char*)Es + byt) = u;
    }
    __syncthreads();

    const int frow = lane & 15;
    const int kq   = lane >> 4;

    bf16x8 efrag[2][2];
#pragma unroll
    for (int nc = 0; nc < 2; ++nc) {
        int brow = wave * 32 + nc * 16 + frow;
        int base = brow * 128 + kq * 16;
        int swz  = (brow & 7) << 4;
        efrag[nc][0] = *(const bf16x8*)((const char*)Es + ((base) ^ swz));
        efrag[nc][1] = *(const bf16x8*)((const char*)Es + ((base + 64) ^ swz));
    }
    __syncthreads();   // efrag hoist complete -> Es dead, Cs may overwrite

    const unsigned short* xp = Xb + (size_t)(mrow0 + frow) * kD + kq * 8;
    const bool ncol_ok = (n0 + lane * 4 + 3) < kItems;

    bf16x8 xc0 = *(const bf16x8*)(xp);
    bf16x8 xc1 = *(const bf16x8*)(xp + 32);

    for (int t = 0; t < NITER; ++t) {
        bf16x8 xn0, xn1;
        if (t + 1 < NITER) {
            xn0 = *(const bf16x8*)(xp + (size_t)(t + 1) * MROWS * kD);
            xn1 = *(const bf16x8*)(xp + (size_t)(t + 1) * MROWS * kD + 32);
        }

        // store previous tile (retires under this iter's compute)
        if (t > 0) {
            CsRow* Csp = ((t - 1) & 1) ? Cs1 : Cs0;
            const int mbase = mrow0 + (t - 1) * MROWS;
#pragma unroll
            for (int rr = 0; rr < 2; ++rr) {
                int r = wave * 2 + rr;
                f32x4v v = *(const f32x4v*)&Csp[r][lane * 4];
                if (ncol_ok)
                    __builtin_nontemporal_store(v,
                        (f32x4v*)(out + (size_t)(mbase + r) * kItems + n0 + lane * 4));
            }
        }

        f32x4v acc[2];
#pragma unroll
        for (int nc = 0; nc < 2; ++nc) {
            acc[nc] = (f32x4v){0.f, 0.f, 0.f, 0.f};
            acc[nc] = __builtin_amdgcn_mfma_f32_16x16x32_bf16(efrag[nc][0], xc0, acc[nc], 0, 0, 0);
            acc[nc] = __builtin_amdgcn_mfma_f32_16x16x32_bf16(efrag[nc][1], xc1, acc[nc], 0, 0, 0);
        }

        {
            CsRow* Csc = (t & 1) ? Cs1 : Cs0;
#pragma unroll
            for (int nc = 0; nc < 2; ++nc)
                *(f32x4v*)&Csc[frow][wave * 32 + nc * 16 + kq * 4] = acc[nc];
        }

        __builtin_amdgcn_sched_barrier(0);
        asm volatile("s_waitcnt lgkmcnt(0)" ::: "memory");
        __builtin_amdgcn_s_barrier();
        __builtin_amdgcn_sched_barrier(0);

        xc0 = xn0; xc1 = xn1;
    }

    {
        CsRow* Csp = ((NITER - 1) & 1) ? Cs1 : Cs0;
        const int mbase = mrow0 + (NITER - 1) * MROWS;
#pragma unroll
        for (int rr = 0; rr < 2; ++rr) {
            int r = wave * 2 + rr;
            f32x4v v = *(const f32x4v*)&Csp[r][lane * 4];
            if (ncol_ok)
                __builtin_nontemporal_store(v,
                    (f32x4v*)(out + (size_t)(mbase + r) * kItems + n0 + lane * 4));
        }
    }
}

extern "C" void kernel_launch(void* const* d_in, const int* in_sizes, int n_in,
                              void* d_out, int out_size, void* d_ws, size_t ws_size,
                              hipStream_t stream) {
    const int*   item_ids = (const int*)d_in[0];
    const float* emb      = (const float*)d_in[1];
    const float* pos_emb  = (const float*)d_in[2];
    const float* Wq       = (const float*)d_in[3];
    const float* Wk       = (const float*)d_in[4];
    const float* Wv       = (const float*)d_in[5];
    const float* W1       = (const float*)d_in[6];
    const float* b1       = (const float*)d_in[7];
    const float* W2       = (const float*)d_in[8];
    const float* b2       = (const float*)d_in[9];
    const float* ln_g     = (const float*)d_in[10];
    const float* ln_b     = (const float*)d_in[11];

    unsigned short* Xb = (unsigned short*)d_ws;   // [B*S, D] bf16, 0.8 MB
    float* out = (float*)d_out;

    transformer_kernel<<<kB, 512, 0, stream>>>(item_ids, emb, pos_emb,
                                               Wq, Wk, Wv, W1, b1, W2, b2,
                                               ln_g, ln_b, Xb);
    dim3 grid(GRIDX, 2);   // 200 x 2 (8 idle pad blocks)
    logits_kernel<<<grid, 512, 0, stream>>>(Xb, emb, out);
}